// Round 11
// baseline (654.828 us; speedup 1.0000x reference)
//
#include <hip/hip_runtime.h>
#include <stdint.h>

#define NM 128    // matrix dim / electrons
#define NT 1024   // 2 matrices/block: waves 0-7 -> mat 0, waves 8-15 -> mat 1.
                  // Within a matrix: wave wm owns cols [16wm..16wm+15];
                  // lane l owns rows l, l+64.  sv[j] = (S[l][c0+j], S[l+64][c0+j])

typedef float v2f __attribute__((ext_vector_type(2)));

__device__ __forceinline__ float readlane_f(float v, int lane) {
    return __int_as_float(__builtin_amdgcn_readlane(__float_as_int(v), lane));
}

// Full 64-lane unsigned max via DPP (VALU pipe); result valid in lane 63.
__device__ __forceinline__ unsigned wave_max_dpp(unsigned x) {
    int v = (int)x;
#define DPP_STEP(ctrl) \
    { int o = __builtin_amdgcn_update_dpp(0, v, ctrl, 0xf, 0xf, true); \
      v = ((unsigned)o > (unsigned)v) ? o : v; }
    DPP_STEP(0x111)  // row_shr:1
    DPP_STEP(0x112)  // row_shr:2
    DPP_STEP(0x114)  // row_shr:4
    DPP_STEP(0x118)  // row_shr:8
    DPP_STEP(0x142)  // row_bcast:15
    DPP_STEP(0x143)  // row_bcast:31
#undef DPP_STEP
    return (unsigned)v;
}

__device__ __forceinline__ unsigned pack_key(float v, int r) {
    // monotone in |v|; drop 6 mantissa LSBs to make room for the 7-bit row id
    return (((__float_as_uint(v) & 0x7fffffffu) >> 6) << 7) | (unsigned)r;
}

// max(ka,kb) over the wave, broadcast to all lanes (uniform result)
__device__ __forceinline__ unsigned argmax_bcast(unsigned ka, unsigned kb) {
    const unsigned m = wave_max_dpp(ka > kb ? ka : kb);
    return (unsigned)__builtin_amdgcn_readlane((int)m, 63);
}

// read pivot row p's element of a (row r0, row r1) register pair; p uniform
__device__ __forceinline__ float sel_readlane(v2f c, int p) {
    return (p < 64) ? readlane_f(c.x, p) : readlane_f(c.y, p - 64);
}

// one elimination step on the 16-col slab: readlane+pk_fma, consumed
// immediately to keep the live set flat (64-VGPR budget).
__device__ __forceinline__ void extract_apply16(v2f (&sv)[16], int p, v2f lm) {
    if (p < 64) {
#pragma unroll
        for (int j = 0; j < 16; ++j) {
            const float u = readlane_f(sv[j].x, p);
            sv[j] = __builtin_elementwise_fma((v2f){-u, -u}, lm, sv[j]);
        }
    } else {
#pragma unroll
        for (int j = 0; j < 16; ++j) {
            const float u = readlane_f(sv[j].y, p - 64);
            sv[j] = __builtin_elementwise_fma((v2f){-u, -u}, lm, sv[j]);
        }
    }
}

// look-ahead: locally factor 4 cols sv[B..B+3] IN PLACE (dead next round),
// publishing pre-multiplied+pre-zeroed multipliers, keys, exact pivots.
template<int B>
__device__ __forceinline__ void lookahead4(v2f (&sv)[16], bool e0, bool e1,
                                           int r0, int r1, int l,
                                           float2 (*colvN)[64],
                                           uint4* keySlot, float4* pivSlot) {
    unsigned kk[4]; float pv[4];
#pragma unroll
    for (int i = 0; i < 4; ++i) {
        const v2f c = sv[B + i];
        const unsigned key = argmax_bcast(e0 ? 0u : pack_key(c.x, r0),
                                          e1 ? 0u : pack_key(c.y, r1));
        const int pu = __builtin_amdgcn_readfirstlane((int)(key & 127u));
        const float piv = sel_readlane(c, pu);
        const float rcp = __builtin_amdgcn_rcpf(piv);
        e0 = e0 || (r0 == pu);
        e1 = e1 || (r1 == pu);
        const v2f lm = { e0 ? 0.0f : c.x * rcp, e1 ? 0.0f : c.y * rcp };
        colvN[i][l] = make_float2(lm.x, lm.y);
#pragma unroll
        for (int m = i + 1; m < 4; ++m) {
            const float u = sel_readlane(sv[B + m], pu);
            sv[B + m] = __builtin_elementwise_fma((v2f){-u, -u}, lm, sv[B + m]);
        }
        kk[i] = key; pv[i] = piv;
    }
    if (l == 0) {
        *keySlot = make_uint4(kk[0], kk[1], kk[2], kk[3]);
        *pivSlot = make_float4(pv[0], pv[1], pv[2], pv[3]);
    }
}

__global__ __launch_bounds__(NT, 8)
void slater_logdet(const float* __restrict__ rs,
                   const float* __restrict__ kpts,
                   const float* __restrict__ csw,
                   const float* __restrict__ ssw,
                   float* __restrict__ out) {
    // per-matrix buffers; colv[mat][parity][step][lane] = multiplier pair
    // {row l, row l+64} — owner lane computed exactly the consumer lane's rows.
    __shared__ float2 colv[2][2][4][64];   // 8 KB
    __shared__ uint4  keys[2][NM / 4];     // write-once pivot-id keys per round
    __shared__ float4 pivs[2][NM / 4];     // write-once exact pivots
    __shared__ float  redf[2][2];

    const int t   = threadIdx.x;
    const int mat = t >> 9;         // matrix within block
    const int tt  = t & 511;
    const int b   = (blockIdx.x << 1) | mat;
    const int wm  = tt >> 6;        // wave id within matrix = 16-col slab id
    const int l   = t & 63;
    const int c0  = wm << 4;
    const int r0  = l, r1 = l + 64;

    v2f sv[16];   // sv[j] = (row r0, row r1) at col c0+j
    {
        const float x0 = rs[(b * NM + r0) * 3 + 0];
        const float y0 = rs[(b * NM + r0) * 3 + 1];
        const float z0 = rs[(b * NM + r0) * 3 + 2];
        const float x1 = rs[(b * NM + r1) * 3 + 0];
        const float y1 = rs[(b * NM + r1) * 3 + 1];
        const float z1 = rs[(b * NM + r1) * 3 + 2];
#pragma unroll
        for (int j = 0; j < 16; ++j) {
            const int m = c0 + j;  // wave-uniform -> scalar loads
            const float kx = kpts[m * 3 + 0], ky = kpts[m * 3 + 1], kz = kpts[m * 3 + 2];
            const float cw = csw[m], sw = ssw[m];
            float sn, cn;
            __sincosf(kx * x0 + ky * y0 + kz * z0, &sn, &cn);
            sv[j].x = cw * cn - sw * sn;
            __sincosf(kx * x1 + ky * y1 + kz * z1, &sn, &cn);
            sv[j].y = cw * cn - sw * sn;
        }
    }

    bool elim0 = false, elim1 = false;

    // ---- bootstrap: wave 0 of each matrix factors cols 0-3 from COPIES ----
    if (wm == 0) {
        v2f c[4] = { sv[0], sv[1], sv[2], sv[3] };
        bool e0 = false, e1 = false;
        unsigned kk[4]; float pv[4];
#pragma unroll
        for (int i = 0; i < 4; ++i) {
            const unsigned key = argmax_bcast(e0 ? 0u : pack_key(c[i].x, r0),
                                             e1 ? 0u : pack_key(c[i].y, r1));
            const int pu = __builtin_amdgcn_readfirstlane((int)(key & 127u));
            const float piv = sel_readlane(c[i], pu);
            const float rcp = __builtin_amdgcn_rcpf(piv);
            e0 = e0 || (r0 == pu);
            e1 = e1 || (r1 == pu);
            const v2f lm = { e0 ? 0.0f : c[i].x * rcp, e1 ? 0.0f : c[i].y * rcp };
            colv[mat][0][i][l] = make_float2(lm.x, lm.y);
#pragma unroll
            for (int m = i + 1; m < 4; ++m) {
                const float u = sel_readlane(c[m], pu);
                c[m] = __builtin_elementwise_fma((v2f){-u, -u}, lm, c[m]);
            }
            kk[i] = key; pv[i] = piv;
        }
        if (l == 0) {
            keys[mat][0] = make_uint4(kk[0], kk[1], kk[2], kk[3]);
            pivs[mat][0] = make_float4(pv[0], pv[1], pv[2], pv[3]);
        }
    }
    __syncthreads();

    // ---- main loop: 31 rounds, one barrier per 4 steps, 2 matrices/barrier ----
    // Wave wm owns rounds 4wm..4wm+3; its last lookahead is during round 4wm+2.
    // Round 31 is never executed (its steps only touch its own pivot cols,
    // factored during round 30's lookahead) but IS published (pivs[31]).
    const int liveEnd = (4 * wm + 2 < 30) ? 4 * wm + 2 : 30;
    int rd = 0;
    for (; rd <= liveEnd; ++rd) {
        const uint4 kk = keys[mat][rd];
        const int p0 = __builtin_amdgcn_readfirstlane((int)(kk.x & 127u));
        const int p1 = __builtin_amdgcn_readfirstlane((int)(kk.y & 127u));
        const int p2 = __builtin_amdgcn_readfirstlane((int)(kk.z & 127u));
        const int p3 = __builtin_amdgcn_readfirstlane((int)(kk.w & 127u));
        elim0 |= (r0 == p0) | (r0 == p1) | (r0 == p2) | (r0 == p3);
        elim1 |= (r1 == p0) | (r1 == p1) | (r1 == p2) | (r1 == p3);

        const int par = rd & 1;
        const float2 la0 = colv[mat][par][0][l];
        const float2 la1 = colv[mat][par][1][l];
        const float2 la2 = colv[mat][par][2][l];
        const float2 la3 = colv[mat][par][3][l];

        extract_apply16(sv, p0, (v2f){la0.x, la0.y});
        extract_apply16(sv, p1, (v2f){la1.x, la1.y});
        extract_apply16(sv, p2, (v2f){la2.x, la2.y});
        extract_apply16(sv, p3, (v2f){la3.x, la3.y});

        // ---- look-ahead publish of round rd+1 (one owner wave per matrix) ----
        const int rr = rd + 1;
        if (rr < NM / 4 && wm == (rr >> 2)) {
            float2 (*cn)[64] = colv[mat][rr & 1];
            uint4*  ks = &keys[mat][rr];
            float4* ps = &pivs[mat][rr];
            switch (rr & 3) {
                case 0: lookahead4<0 >(sv, elim0, elim1, r0, r1, l, cn, ks, ps); break;
                case 1: lookahead4<4 >(sv, elim0, elim1, r0, r1, l, cn, ks, ps); break;
                case 2: lookahead4<8 >(sv, elim0, elim1, r0, r1, l, cn, ks, ps); break;
                default: lookahead4<12>(sv, elim0, elim1, r0, r1, l, cn, ks, ps); break;
            }
        }
        __syncthreads();
    }
    for (; rd < 31; ++rd) __syncthreads();   // dead waves: barrier-only

    // ---- log|det| = sum log|piv_k| over the write-once pivs array ----
    float lg = 0.0f;
    if (tt < NM) {
        const float4 pb = pivs[mat][tt >> 2];
        const int cc = tt & 3;
        const float pv = (cc == 0) ? pb.x : (cc == 1) ? pb.y : (cc == 2) ? pb.z : pb.w;
        lg = __logf(fabsf(pv));
#pragma unroll
        for (int off = 32; off > 0; off >>= 1)
            lg += __shfl_xor(lg, off, 64);
        if ((l == 0) && (tt >> 6) < 2) redf[mat][tt >> 6] = lg;
    }
    __syncthreads();
    if (tt == 0) out[b] = redf[mat][0] + redf[mat][1];
}

extern "C" void kernel_launch(void* const* d_in, const int* in_sizes, int n_in,
                              void* d_out, int out_size, void* d_ws, size_t ws_size,
                              hipStream_t stream) {
    const float* rs = (const float*)d_in[0];
    const float* kp = (const float*)d_in[1];
    const float* cs = (const float*)d_in[2];
    const float* ss = (const float*)d_in[3];
    float* out = (float*)d_out;
    const int batch = in_sizes[0] / (NM * 3);  // 4096
    slater_logdet<<<dim3(batch / 2), dim3(NT), 0, stream>>>(rs, kp, cs, ss, out);
}

// Round 12
// 444.798 us; speedup vs baseline: 1.4722x; 1.4722x over previous
//
#include <hip/hip_runtime.h>
#include <stdint.h>

#define NM 128    // matrix dim / electrons
#define NT 1024   // 16 waves; wave w owns cols [8w..8w+7]; lane l owns rows l, l+64
                  // sv[j] = (S[l][8w+j], S[l+64][8w+j]) — 16 VGPRs of state

typedef float v2f __attribute__((ext_vector_type(2)));

__device__ __forceinline__ float readlane_f(float v, int lane) {
    return __int_as_float(__builtin_amdgcn_readlane(__float_as_int(v), lane));
}

// Full 64-lane unsigned max via DPP (VALU pipe); result valid in lane 63.
__device__ __forceinline__ unsigned wave_max_dpp(unsigned x) {
    int v = (int)x;
#define DPP_STEP(ctrl) \
    { int o = __builtin_amdgcn_update_dpp(0, v, ctrl, 0xf, 0xf, true); \
      v = ((unsigned)o > (unsigned)v) ? o : v; }
    DPP_STEP(0x111)  // row_shr:1
    DPP_STEP(0x112)  // row_shr:2
    DPP_STEP(0x114)  // row_shr:4
    DPP_STEP(0x118)  // row_shr:8
    DPP_STEP(0x142)  // row_bcast:15
    DPP_STEP(0x143)  // row_bcast:31
#undef DPP_STEP
    return (unsigned)v;
}

__device__ __forceinline__ unsigned pack_key(float v, int r) {
    // monotone in |v|; drop 6 mantissa LSBs to make room for the 7-bit row id
    return (((__float_as_uint(v) & 0x7fffffffu) >> 6) << 7) | (unsigned)r;
}

// max(ka,kb) over the wave, broadcast to all lanes (uniform result)
__device__ __forceinline__ unsigned argmax_bcast(unsigned ka, unsigned kb) {
    const unsigned m = wave_max_dpp(ka > kb ? ka : kb);
    return (unsigned)__builtin_amdgcn_readlane((int)m, 63);
}

// read pivot row p's element of a (row r0, row r1) register pair; p uniform
__device__ __forceinline__ float sel_readlane(v2f c, int p) {
    return (p < 64) ? readlane_f(c.x, p) : readlane_f(c.y, p - 64);
}

// one elimination step: batch the 8 readlanes (independent) then 8 pk_fma
__device__ __forceinline__ void extract_apply8(v2f (&sv)[8], int p, v2f lm) {
    float u[8];
    if (p < 64) {
#pragma unroll
        for (int j = 0; j < 8; ++j) u[j] = readlane_f(sv[j].x, p);
    } else {
#pragma unroll
        for (int j = 0; j < 8; ++j) u[j] = readlane_f(sv[j].y, p - 64);
    }
#pragma unroll
    for (int j = 0; j < 8; ++j)
        sv[j] = __builtin_elementwise_fma((v2f){-u[j], -u[j]}, lm, sv[j]);
}

__global__ __launch_bounds__(NT, 8)
void slater_logdet(const float* __restrict__ rs,
                   const float* __restrict__ kpts,
                   const float* __restrict__ csw,
                   const float* __restrict__ ssw,
                   float* __restrict__ out) {
    // colv[parity][step][lane]: pre-multiplied, pre-zeroed multiplier pair
    // {row l, row l+64} — 0-conflict layout (measured R10).
    __shared__ float2 colv[2][8][64];          // 8 KB
    __shared__ unsigned keysF[NM];             // write-once pivot keys per step
    __shared__ float    pivsF[NM];             // write-once exact pivots
    __shared__ ulonglong2 masks[NM / 8];       // per-group new-pivot row ballots
    __shared__ float    redf[2];

    const int t  = threadIdx.x;
    const int b  = blockIdx.x;
    const int w  = t >> 6;    // wave id = 8-col slab id = panel-group id
    const int l  = t & 63;
    const int c0 = w << 3;
    const int r0 = l, r1 = l + 64;

    v2f sv[8];   // sv[j] = (row r0, row r1) at col c0+j
    {
        const float x0 = rs[(b * NM + r0) * 3 + 0];
        const float y0 = rs[(b * NM + r0) * 3 + 1];
        const float z0 = rs[(b * NM + r0) * 3 + 2];
        const float x1 = rs[(b * NM + r1) * 3 + 0];
        const float y1 = rs[(b * NM + r1) * 3 + 1];
        const float z1 = rs[(b * NM + r1) * 3 + 2];
#pragma unroll
        for (int j = 0; j < 8; ++j) {
            const int m = c0 + j;  // wave-uniform -> scalar loads
            const float kx = kpts[m * 3 + 0], ky = kpts[m * 3 + 1], kz = kpts[m * 3 + 2];
            const float cw = csw[m], sw = ssw[m];
            float sn, cn;
            __sincosf(kx * x0 + ky * y0 + kz * z0, &sn, &cn);
            sv[j].x = cw * cn - sw * sn;
            __sincosf(kx * x1 + ky * y1 + kz * z1, &sn, &cn);
            sv[j].y = cw * cn - sw * sn;
        }
    }

    bool elim0 = false, elim1 = false;

    // ---- lookahead8 as a lambda: factor own slab in place, publish group g ----
    auto lookahead8 = [&](int g) {
        const bool e0in = elim0, e1in = elim1;
#pragma unroll
        for (int i = 0; i < 8; ++i) {
            const v2f c = sv[i];
            const unsigned key = argmax_bcast(elim0 ? 0u : pack_key(c.x, r0),
                                              elim1 ? 0u : pack_key(c.y, r1));
            const int pu = __builtin_amdgcn_readfirstlane((int)(key & 127u));
            const float piv = sel_readlane(c, pu);
            const float rcp = __builtin_amdgcn_rcpf(piv);
            elim0 = elim0 || (r0 == pu);
            elim1 = elim1 || (r1 == pu);
            const v2f lm = { elim0 ? 0.0f : c.x * rcp,
                             elim1 ? 0.0f : c.y * rcp };
            colv[g & 1][i][l] = make_float2(lm.x, lm.y);
#pragma unroll
            for (int m = i + 1; m < 8; ++m) {
                const float u = sel_readlane(sv[m], pu);
                sv[m] = __builtin_elementwise_fma((v2f){-u, -u}, lm, sv[m]);
            }
            if (l == 0) { keysF[8 * g + i] = key; pivsF[8 * g + i] = piv; }
        }
        const unsigned long long b0 = __ballot(elim0 && !e0in);
        const unsigned long long b1 = __ballot(elim1 && !e1in);
        if (l == 0) masks[g] = make_ulonglong2(b0, b1);
    };

    // ---- bootstrap: wave 0 factors & publishes group 0 ----
    if (w == 0) lookahead8(0);
    __syncthreads();

    // ---- main loop: 15 rounds; round rd applies group rd; owner = wave rd+1.
    // Wave w is consumer in rounds 0..w-2, owner in round w-1, then retires.
    int rd = 0;
    const int myRounds = w;                 // rounds this wave participates in
    for (; rd < myRounds; ++rd) {
        // front-matter: 8 pivot ids (b128 reads) + elim masks (b128 read)
        const uint4 ka = *(const uint4*)&keysF[8 * rd];
        const uint4 kb = *(const uint4*)&keysF[8 * rd + 4];
        const int p0 = __builtin_amdgcn_readfirstlane((int)(ka.x & 127u));
        const int p1 = __builtin_amdgcn_readfirstlane((int)(ka.y & 127u));
        const int p2 = __builtin_amdgcn_readfirstlane((int)(ka.z & 127u));
        const int p3 = __builtin_amdgcn_readfirstlane((int)(ka.w & 127u));
        const int p4 = __builtin_amdgcn_readfirstlane((int)(kb.x & 127u));
        const int p5 = __builtin_amdgcn_readfirstlane((int)(kb.y & 127u));
        const int p6 = __builtin_amdgcn_readfirstlane((int)(kb.z & 127u));
        const int p7 = __builtin_amdgcn_readfirstlane((int)(kb.w & 127u));
        const ulonglong2 mk = masks[rd];
        elim0 = elim0 || (((mk.x >> l) & 1ull) != 0);
        elim1 = elim1 || (((mk.y >> l) & 1ull) != 0);

        const int par = rd & 1;
        const float2 la0 = colv[par][0][l];
        const float2 la1 = colv[par][1][l];
        const float2 la2 = colv[par][2][l];
        const float2 la3 = colv[par][3][l];
        const float2 la4 = colv[par][4][l];
        const float2 la5 = colv[par][5][l];
        const float2 la6 = colv[par][6][l];
        const float2 la7 = colv[par][7][l];

        extract_apply8(sv, p0, (v2f){la0.x, la0.y});
        extract_apply8(sv, p1, (v2f){la1.x, la1.y});
        extract_apply8(sv, p2, (v2f){la2.x, la2.y});
        extract_apply8(sv, p3, (v2f){la3.x, la3.y});
        extract_apply8(sv, p4, (v2f){la4.x, la4.y});
        extract_apply8(sv, p5, (v2f){la5.x, la5.y});
        extract_apply8(sv, p6, (v2f){la6.x, la6.y});
        extract_apply8(sv, p7, (v2f){la7.x, la7.y});

        if (rd == w - 1) lookahead8(rd + 1);  // owner: factor own slab, publish

        __syncthreads();
    }
    for (; rd < 15; ++rd) __syncthreads();   // retired waves: barrier-only

    // ---- log|det| = sum log|piv_k| over the write-once pivsF array ----
    float lg = 0.0f;
    if (t < NM) {
        lg = __logf(fabsf(pivsF[t]));
#pragma unroll
        for (int off = 32; off > 0; off >>= 1)
            lg += __shfl_xor(lg, off, 64);
        if ((t & 63) == 0) redf[t >> 6] = lg;
    }
    __syncthreads();
    if (t == 0) out[b] = redf[0] + redf[1];
}

extern "C" void kernel_launch(void* const* d_in, const int* in_sizes, int n_in,
                              void* d_out, int out_size, void* d_ws, size_t ws_size,
                              hipStream_t stream) {
    const float* rs = (const float*)d_in[0];
    const float* kp = (const float*)d_in[1];
    const float* cs = (const float*)d_in[2];
    const float* ss = (const float*)d_in[3];
    float* out = (float*)d_out;
    const int batch = in_sizes[0] / (NM * 3);  // 4096
    slater_logdet<<<dim3(batch), dim3(NT), 0, stream>>>(rs, kp, cs, ss, out);
}

// Round 13
// 400.847 us; speedup vs baseline: 1.6336x; 1.1096x over previous
//
#include <hip/hip_runtime.h>
#include <stdint.h>

#define NM 128   // matrix dim / electrons
#define NT 512   // 8 waves; wave w owns cols [16w..16w+15]; lane l owns rows l, l+64
                 // sv[j] = (S[l][16w+j], S[l+64][16w+j]) — 32 VGPRs of state

typedef float v2f __attribute__((ext_vector_type(2)));

__device__ __forceinline__ float readlane_f(float v, int lane) {
    return __int_as_float(__builtin_amdgcn_readlane(__float_as_int(v), lane));
}

// Full 64-lane unsigned max via DPP (VALU pipe); result valid in lane 63.
__device__ __forceinline__ unsigned wave_max_dpp(unsigned x) {
    int v = (int)x;
#define DPP_STEP(ctrl) \
    { int o = __builtin_amdgcn_update_dpp(0, v, ctrl, 0xf, 0xf, true); \
      v = ((unsigned)o > (unsigned)v) ? o : v; }
    DPP_STEP(0x111)  // row_shr:1
    DPP_STEP(0x112)  // row_shr:2
    DPP_STEP(0x114)  // row_shr:4
    DPP_STEP(0x118)  // row_shr:8
    DPP_STEP(0x142)  // row_bcast:15
    DPP_STEP(0x143)  // row_bcast:31
#undef DPP_STEP
    return (unsigned)v;
}

__device__ __forceinline__ unsigned pack_key(float v, int r) {
    // monotone in |v|; drop 6 mantissa LSBs to make room for the 7-bit row id
    return (((__float_as_uint(v) & 0x7fffffffu) >> 6) << 7) | (unsigned)r;
}

// max(ka,kb) over the wave, broadcast to all lanes (uniform result)
__device__ __forceinline__ unsigned argmax_bcast(unsigned ka, unsigned kb) {
    const unsigned m = wave_max_dpp(ka > kb ? ka : kb);
    return (unsigned)__builtin_amdgcn_readlane((int)m, 63);
}

// read pivot row p's element of a (row r0, row r1) register pair; p uniform
__device__ __forceinline__ float sel_readlane(v2f c, int p) {
    return (p < 64) ? readlane_f(c.x, p) : readlane_f(c.y, p - 64);
}

// one elimination step on cols [B, B+N): batch N readlanes then N pk_fma
template<int B, int N>
__device__ __forceinline__ void extract_apply(v2f (&sv)[16], int p, v2f lm) {
    float u[N];
    if (p < 64) {
#pragma unroll
        for (int j = 0; j < N; ++j) u[j] = readlane_f(sv[B + j].x, p);
    } else {
#pragma unroll
        for (int j = 0; j < N; ++j) u[j] = readlane_f(sv[B + j].y, p - 64);
    }
#pragma unroll
    for (int j = 0; j < N; ++j)
        sv[B + j] = __builtin_elementwise_fma((v2f){-u[j], -u[j]}, lm, sv[B + j]);
}

// factor 8 cols sv[B..B+7] in place (they die afterwards), publishing
// pre-multiplied+pre-zeroed multipliers, keys, exact pivots, elim ballots.
template<int B>
__device__ __forceinline__ void lookahead8(v2f (&sv)[16], bool& elim0, bool& elim1,
                                           int r0, int r1, int l, int g,
                                           float2 (*colvg)[64],
                                           unsigned* keysF, float* pivsF,
                                           ulonglong2* masks) {
    const bool e0in = elim0, e1in = elim1;
#pragma unroll
    for (int i = 0; i < 8; ++i) {
        const v2f c = sv[B + i];
        const unsigned key = argmax_bcast(elim0 ? 0u : pack_key(c.x, r0),
                                          elim1 ? 0u : pack_key(c.y, r1));
        const int pu = __builtin_amdgcn_readfirstlane((int)(key & 127u));
        const float piv = sel_readlane(c, pu);
        const float rcp = __builtin_amdgcn_rcpf(piv);
        elim0 = elim0 || (r0 == pu);
        elim1 = elim1 || (r1 == pu);
        const v2f lm = { elim0 ? 0.0f : c.x * rcp,
                         elim1 ? 0.0f : c.y * rcp };
        colvg[i][l] = make_float2(lm.x, lm.y);
#pragma unroll
        for (int m = i + 1; m < 8; ++m) {
            const float u = sel_readlane(sv[B + m], pu);
            sv[B + m] = __builtin_elementwise_fma((v2f){-u, -u}, lm, sv[B + m]);
        }
        if (l == 0) { keysF[8 * g + i] = key; pivsF[8 * g + i] = piv; }
    }
    const unsigned long long b0 = __ballot(elim0 && !e0in);
    const unsigned long long b1 = __ballot(elim1 && !e1in);
    if (l == 0) masks[g] = make_ulonglong2(b0, b1);
}

__global__ __launch_bounds__(NT, 6)   // VGPR cap ~85: fits sv[16]+temps, 3 blocks/CU
void slater_logdet(const float* __restrict__ rs,
                   const float* __restrict__ kpts,
                   const float* __restrict__ csw,
                   const float* __restrict__ ssw,
                   float* __restrict__ out) {
    __shared__ float2 colv[2][8][64];      // pre-multiplied, pre-zeroed pairs
    __shared__ unsigned keysF[NM];         // write-once pivot keys per step
    __shared__ float    pivsF[NM];         // write-once exact pivots
    __shared__ ulonglong2 masks[NM / 8];   // per-group new-pivot row ballots
    __shared__ float    redf[2];

    const int t  = threadIdx.x;
    const int b  = blockIdx.x;
    const int w  = t >> 6;    // wave id = 16-col slab id (groups 2w, 2w+1)
    const int l  = t & 63;
    const int c0 = w << 4;
    const int r0 = l, r1 = l + 64;

    v2f sv[16];   // sv[j] = (row r0, row r1) at col c0+j
    {
        const float x0 = rs[(b * NM + r0) * 3 + 0];
        const float y0 = rs[(b * NM + r0) * 3 + 1];
        const float z0 = rs[(b * NM + r0) * 3 + 2];
        const float x1 = rs[(b * NM + r1) * 3 + 0];
        const float y1 = rs[(b * NM + r1) * 3 + 1];
        const float z1 = rs[(b * NM + r1) * 3 + 2];
#pragma unroll
        for (int j = 0; j < 16; ++j) {
            const int m = c0 + j;  // wave-uniform -> scalar loads
            const float kx = kpts[m * 3 + 0], ky = kpts[m * 3 + 1], kz = kpts[m * 3 + 2];
            const float cw = csw[m], sw = ssw[m];
            float sn, cn;
            __sincosf(kx * x0 + ky * y0 + kz * z0, &sn, &cn);
            sv[j].x = cw * cn - sw * sn;
            __sincosf(kx * x1 + ky * y1 + kz * z1, &sn, &cn);
            sv[j].y = cw * cn - sw * sn;
        }
    }

    bool elim0 = false, elim1 = false;

    // ---- bootstrap: wave 0 factors & publishes group 0 (its cols 0-7) ----
    if (w == 0)
        lookahead8<0>(sv, elim0, elim1, r0, r1, l, 0, colv[0], keysF, pivsF, masks);
    __syncthreads();

    // ---- main loop: 15 rounds; round rd applies group rd.
    // Wave w: consumer (full 16-col apply) for rd < 2w-1;
    //   rd == 2w-1: full apply + lookahead on cols 0-7  (group 2w);
    //   rd == 2w  : high-half apply + lookahead on cols 8-15 (group 2w+1); retire.
    const int liveEnd = (2 * w < 14) ? 2 * w : 14;
    int rd = 0;
    for (; rd <= liveEnd; ++rd) {
        const uint4 ka = *(const uint4*)&keysF[8 * rd];
        const uint4 kb = *(const uint4*)&keysF[8 * rd + 4];
        const int p0 = __builtin_amdgcn_readfirstlane((int)(ka.x & 127u));
        const int p1 = __builtin_amdgcn_readfirstlane((int)(ka.y & 127u));
        const int p2 = __builtin_amdgcn_readfirstlane((int)(ka.z & 127u));
        const int p3 = __builtin_amdgcn_readfirstlane((int)(ka.w & 127u));
        const int p4 = __builtin_amdgcn_readfirstlane((int)(kb.x & 127u));
        const int p5 = __builtin_amdgcn_readfirstlane((int)(kb.y & 127u));
        const int p6 = __builtin_amdgcn_readfirstlane((int)(kb.z & 127u));
        const int p7 = __builtin_amdgcn_readfirstlane((int)(kb.w & 127u));
        const ulonglong2 mk = masks[rd];
        elim0 = elim0 || (((mk.x >> l) & 1ull) != 0);
        elim1 = elim1 || (((mk.y >> l) & 1ull) != 0);

        const int par = rd & 1;
        const float2 la0 = colv[par][0][l];
        const float2 la1 = colv[par][1][l];
        const float2 la2 = colv[par][2][l];
        const float2 la3 = colv[par][3][l];
        const float2 la4 = colv[par][4][l];
        const float2 la5 = colv[par][5][l];
        const float2 la6 = colv[par][6][l];
        const float2 la7 = colv[par][7][l];

        if (rd < 2 * w) {   // full 16-col apply
            extract_apply<0, 8>(sv, p0, (v2f){la0.x, la0.y});
            extract_apply<8, 8>(sv, p0, (v2f){la0.x, la0.y});
            extract_apply<0, 8>(sv, p1, (v2f){la1.x, la1.y});
            extract_apply<8, 8>(sv, p1, (v2f){la1.x, la1.y});
            extract_apply<0, 8>(sv, p2, (v2f){la2.x, la2.y});
            extract_apply<8, 8>(sv, p2, (v2f){la2.x, la2.y});
            extract_apply<0, 8>(sv, p3, (v2f){la3.x, la3.y});
            extract_apply<8, 8>(sv, p3, (v2f){la3.x, la3.y});
            extract_apply<0, 8>(sv, p4, (v2f){la4.x, la4.y});
            extract_apply<8, 8>(sv, p4, (v2f){la4.x, la4.y});
            extract_apply<0, 8>(sv, p5, (v2f){la5.x, la5.y});
            extract_apply<8, 8>(sv, p5, (v2f){la5.x, la5.y});
            extract_apply<0, 8>(sv, p6, (v2f){la6.x, la6.y});
            extract_apply<8, 8>(sv, p6, (v2f){la6.x, la6.y});
            extract_apply<0, 8>(sv, p7, (v2f){la7.x, la7.y});
            extract_apply<8, 8>(sv, p7, (v2f){la7.x, la7.y});
        } else {            // rd == 2w: cols 0-7 already factored, apply high half
            extract_apply<8, 8>(sv, p0, (v2f){la0.x, la0.y});
            extract_apply<8, 8>(sv, p1, (v2f){la1.x, la1.y});
            extract_apply<8, 8>(sv, p2, (v2f){la2.x, la2.y});
            extract_apply<8, 8>(sv, p3, (v2f){la3.x, la3.y});
            extract_apply<8, 8>(sv, p4, (v2f){la4.x, la4.y});
            extract_apply<8, 8>(sv, p5, (v2f){la5.x, la5.y});
            extract_apply<8, 8>(sv, p6, (v2f){la6.x, la6.y});
            extract_apply<8, 8>(sv, p7, (v2f){la7.x, la7.y});
        }

        if (rd == 2 * w - 1)
            lookahead8<0>(sv, elim0, elim1, r0, r1, l, rd + 1,
                          colv[(rd + 1) & 1], keysF, pivsF, masks);
        if (rd == 2 * w)
            lookahead8<8>(sv, elim0, elim1, r0, r1, l, rd + 1,
                          colv[(rd + 1) & 1], keysF, pivsF, masks);

        __syncthreads();
    }
    for (; rd < 15; ++rd) __syncthreads();   // retired waves: barrier-only

    // ---- log|det| = sum log|piv_k| over the write-once pivsF array ----
    float lg = 0.0f;
    if (t < NM) {
        lg = __logf(fabsf(pivsF[t]));
#pragma unroll
        for (int off = 32; off > 0; off >>= 1)
            lg += __shfl_xor(lg, off, 64);
        if ((t & 63) == 0) redf[t >> 6] = lg;
    }
    __syncthreads();
    if (t == 0) out[b] = redf[0] + redf[1];
}

extern "C" void kernel_launch(void* const* d_in, const int* in_sizes, int n_in,
                              void* d_out, int out_size, void* d_ws, size_t ws_size,
                              hipStream_t stream) {
    const float* rs = (const float*)d_in[0];
    const float* kp = (const float*)d_in[1];
    const float* cs = (const float*)d_in[2];
    const float* ss = (const float*)d_in[3];
    float* out = (float*)d_out;
    const int batch = in_sizes[0] / (NM * 3);  // 4096
    slater_logdet<<<dim3(batch), dim3(NT), 0, stream>>>(rs, kp, cs, ss, out);
}